// Round 1
// baseline (2130.170 us; speedup 1.0000x reference)
//
#include <hip/hip_runtime.h>

#define B_  4
#define S_  1024
#define H_  32
#define D_  128
#define E_  4096
#define T_  4096
#define NB_ 64
#define BS_ 16

typedef __attribute__((ext_vector_type(8))) __bf16 bf16x8;
typedef __attribute__((ext_vector_type(4))) __bf16 bf16x4;
typedef __attribute__((ext_vector_type(4))) float f32x4;

// ---------------------------------------------------------------- converts
__global__ __launch_bounds__(256) void k_convert_hs(const float* __restrict__ x,
                                                    __bf16* __restrict__ y, int n4) {
  int i = blockIdx.x * 256 + threadIdx.x;
  if (i < n4) {
    float4 v = ((const float4*)x)[i];
    bf16x4 o;
    o[0] = (__bf16)v.x; o[1] = (__bf16)v.y; o[2] = (__bf16)v.z; o[3] = (__bf16)v.w;
    ((bf16x4*)y)[i] = o;
  }
}

// W: [nm][E][E] fp32 (e,f) -> WT: [nm][E][E] bf16 transposed (f,e)
__global__ __launch_bounds__(256) void k_transpose_w(const float* __restrict__ W,
                                                     __bf16* __restrict__ WT) {
  __shared__ float tile[32][33];
  const float* Wm = W + (size_t)blockIdx.z * E_ * E_;
  __bf16* WTm = WT + (size_t)blockIdx.z * E_ * E_;
  int e0 = blockIdx.x * 32, f0 = blockIdx.y * 32;
  int tx = threadIdx.x & 31, ty = threadIdx.x >> 5;
  for (int i = ty; i < 32; i += 8) tile[i][tx] = Wm[(size_t)(e0 + i) * E_ + f0 + tx];
  __syncthreads();
  for (int i = ty; i < 32; i += 8) WTm[(size_t)(f0 + i) * E_ + e0 + tx] = (__bf16)tile[tx][i];
}

// v [b][h][s][d] -> vT [b][h][d][s]  (bf16)
__global__ __launch_bounds__(256) void k_transpose_v(const __bf16* __restrict__ v,
                                                     __bf16* __restrict__ vT) {
  __shared__ __bf16 tile[32][33];
  size_t bh = blockIdx.z;
  const __bf16* vp = v + bh * S_ * D_;
  __bf16* vtp = vT + bh * S_ * D_;
  int s0 = blockIdx.x * 32, d0 = blockIdx.y * 32;
  int tx = threadIdx.x & 31, ty = threadIdx.x >> 5;
  for (int i = ty; i < 32; i += 8) tile[i][tx] = vp[(size_t)(s0 + i) * D_ + d0 + tx];
  __syncthreads();
  for (int i = ty; i < 32; i += 8) vtp[(size_t)(d0 + i) * S_ + s0 + tx] = tile[tx][i];
}

// ---------------------------------------------------------------- RoPE + cache scatter
__global__ __launch_bounds__(256) void k_rope(__bf16* __restrict__ q, __bf16* __restrict__ k,
                                              const __bf16* __restrict__ v,
                                              const float* __restrict__ cosb,
                                              const float* __restrict__ sinb,
                                              const int* __restrict__ bt,
                                              float* __restrict__ kc, float* __restrict__ vc) {
  int idx = blockIdx.x * 256 + threadIdx.x;   // B*H*S*64 = 2^23 threads
  int j = idx & 63;
  int s = (idx >> 6) & (S_ - 1);
  int h = (idx >> 16) & (H_ - 1);
  int b = idx >> 21;
  size_t base = (((size_t)b * H_ + h) * S_ + s) * D_;
  float c  = cosb[(size_t)(b * S_ + s) * 64 + j];
  float sn = sinb[(size_t)(b * S_ + s) * 64 + j];
  float q1 = (float)q[base + j], q2 = (float)q[base + j + 64];
  float k1 = (float)k[base + j], k2 = (float)k[base + j + 64];
  float q1n = q1 * c - q2 * sn, q2n = q2 * c + q1 * sn;
  float k1n = k1 * c - k2 * sn, k2n = k2 * c + k1 * sn;
  q[base + j] = (__bf16)q1n; q[base + j + 64] = (__bf16)q2n;
  k[base + j] = (__bf16)k1n; k[base + j + 64] = (__bf16)k2n;
  int nb = s >> 4, sb = s & 15;
  int blk = bt[b * NB_ + nb];
  size_t cidx = (((size_t)blk * H_ + h) * BS_ + sb) * D_;
  kc[cidx + j] = k1n; kc[cidx + j + 64] = k2n;
  vc[cidx + j] = (float)v[base + j];
  vc[cidx + j + 64] = (float)v[base + j + 64];
}

// ---------------------------------------------------------------- GEMMs (128x128x32, 4 waves)
// A: [M][K] bf16 row-major; BT: [N][K] bf16 row-major (i.e. B transposed)
#define GEMM_BODY                                                                  \
  __shared__ __align__(16) __bf16 As[128][40];                                     \
  __shared__ __align__(16) __bf16 Bs[128][40];                                     \
  int tid = threadIdx.x;                                                           \
  int wid = tid >> 6, lane = tid & 63, l15 = lane & 15, quad = lane >> 4;          \
  int wy = wid >> 1, wx = wid & 1;                                                 \
  int m0 = blockIdx.x * 128, n0 = blockIdx.y * 128;                                \
  const __bf16* Bp = BT + (size_t)n0 * E_;                                         \
  f32x4 acc[4][4] = {};                                                            \
  for (int k0 = 0; k0 < E_; k0 += 32) {                                            \
    for (int c = tid; c < 1024; c += 256) {                                        \
      int cc = c & 511;                                                            \
      int r = cc >> 2, kp = (cc & 3) * 8;                                          \
      if (c < 512) *(int4*)&As[r][kp] = *(const int4*)&A[(size_t)(m0 + r) * E_ + k0 + kp]; \
      else         *(int4*)&Bs[r][kp] = *(const int4*)&Bp[(size_t)r * E_ + k0 + kp];       \
    }                                                                              \
    __syncthreads();                                                               \
    bf16x8 af[4], bfr[4];                                                          \
    for (int i = 0; i < 4; i++) af[i]  = *(const bf16x8*)&As[wy * 64 + i * 16 + l15][quad * 8]; \
    for (int j = 0; j < 4; j++) bfr[j] = *(const bf16x8*)&Bs[wx * 64 + j * 16 + l15][quad * 8]; \
    for (int i = 0; i < 4; i++)                                                    \
      for (int j = 0; j < 4; j++)                                                  \
        acc[i][j] = __builtin_amdgcn_mfma_f32_16x16x32_bf16(af[i], bfr[j], acc[i][j], 0, 0, 0); \
    __syncthreads();                                                               \
  }

__global__ __launch_bounds__(256) void k_gemm_qkv(const __bf16* __restrict__ A,
                                                  const __bf16* __restrict__ BT,
                                                  __bf16* __restrict__ qkvb) {
  GEMM_BODY
  for (int i = 0; i < 4; i++) {
    int tbase = m0 + wy * 64 + i * 16 + quad * 4;
    for (int j = 0; j < 4; j++) {
      int n = n0 + wx * 64 + j * 16 + l15;      // 0..12287
      int kk = n >> 12, nl = n & 4095;
      int h = nl >> 7, d = nl & 127;
      for (int r = 0; r < 4; r++) {
        int t = tbase + r;
        int bb = t >> 10, s = t & 1023;
        size_t idx = ((((size_t)kk * B_ + bb) * H_ + h) * S_ + s) * D_ + d;
        qkvb[idx] = (__bf16)acc[i][j][r];
      }
    }
  }
}

__global__ __launch_bounds__(256) void k_gemm_out(const __bf16* __restrict__ A,
                                                  const __bf16* __restrict__ BT,
                                                  float* __restrict__ out) {
  GEMM_BODY
  for (int i = 0; i < 4; i++) {
    int tbase = m0 + wy * 64 + i * 16 + quad * 4;
    for (int j = 0; j < 4; j++) {
      int n = n0 + wx * 64 + j * 16 + l15;
      for (int r = 0; r < 4; r++)
        out[(size_t)(tbase + r) * E_ + n] = acc[i][j][r];
    }
  }
}

// ---------------------------------------------------------------- flash attention
// q,k: [b][h][s][d] bf16 (post-RoPE); vT: [b][h][d][s] bf16; attn: [t][e] bf16
__global__ __launch_bounds__(256) void k_attn(const __bf16* __restrict__ q,
                                              const __bf16* __restrict__ k,
                                              const __bf16* __restrict__ vT,
                                              __bf16* __restrict__ attn) {
  __shared__ __align__(16) __bf16 Qs[64][136];
  __shared__ __align__(16) __bf16 Ks[64][136];
  __shared__ __align__(16) __bf16 Vs[128][72];
  __shared__ __align__(16) __bf16 Ps[4][16][72];

  int q0 = blockIdx.x * 64;
  int h = blockIdx.y, b = blockIdx.z;
  int tid = threadIdx.x, wid = tid >> 6, lane = tid & 63, l15 = lane & 15, quad = lane >> 4;

  size_t bh = (size_t)b * H_ + h;
  const __bf16* Qp = q + bh * S_ * D_;
  const __bf16* Kp = k + bh * S_ * D_;
  const __bf16* Vp = vT + bh * (size_t)D_ * S_;

  for (int c = tid; c < 1024; c += 256) {
    int r = c >> 4, dp = (c & 15) * 8;
    *(int4*)&Qs[r][dp] = *(const int4*)&Qp[(size_t)(q0 + r) * D_ + dp];
  }
  __syncthreads();
  bf16x8 aq[4];
  for (int ks = 0; ks < 4; ks++) aq[ks] = *(const bf16x8*)&Qs[wid * 16 + l15][ks * 32 + quad * 8];

  float m_run[4], l_run[4];
  f32x4 o_acc[8] = {};
  for (int r = 0; r < 4; r++) { m_run[r] = -1e30f; l_run[r] = 0.f; }
  const float sm_scale = 0.08838834764831845f;

  int kend = q0 + 64;
  for (int sk0 = 0; sk0 < kend; sk0 += 64) {
    __syncthreads();   // previous iter's Ks/Vs reads done
    for (int c = tid; c < 1024; c += 256) {
      int r = c >> 4, dp = (c & 15) * 8;
      *(int4*)&Ks[r][dp] = *(const int4*)&Kp[(size_t)(sk0 + r) * D_ + dp];
    }
    for (int c = tid; c < 1024; c += 256) {
      int d = c >> 3, sp = (c & 7) * 8;
      *(int4*)&Vs[d][sp] = *(const int4*)&Vp[(size_t)d * S_ + sk0 + sp];
    }
    __syncthreads();

    f32x4 st[4] = {};
    for (int nt = 0; nt < 4; nt++)
      for (int ks = 0; ks < 4; ks++) {
        bf16x8 bk = *(const bf16x8*)&Ks[nt * 16 + l15][ks * 32 + quad * 8];
        st[nt] = __builtin_amdgcn_mfma_f32_16x16x32_bf16(aq[ks], bk, st[nt], 0, 0, 0);
      }

    int qg = q0 + wid * 16 + quad * 4;
    float mnew[4], alpha[4];
    for (int r = 0; r < 4; r++) {
      float rmax = -1e30f;
      for (int nt = 0; nt < 4; nt++) {
        int kg = sk0 + nt * 16 + l15;
        float vsc = st[nt][r] * sm_scale;
        if (kg > qg + r) vsc = -1e30f;
        st[nt][r] = vsc;
        rmax = fmaxf(rmax, vsc);
      }
      for (int off = 1; off < 16; off <<= 1) rmax = fmaxf(rmax, __shfl_xor(rmax, off));
      mnew[r] = fmaxf(m_run[r], rmax);
      alpha[r] = __expf(m_run[r] - mnew[r]);
      float s_ = 0.f;
      for (int nt = 0; nt < 4; nt++) {
        float p = __expf(st[nt][r] - mnew[r]);
        st[nt][r] = p;
        s_ += p;
      }
      for (int off = 1; off < 16; off <<= 1) s_ += __shfl_xor(s_, off);
      l_run[r] = l_run[r] * alpha[r] + s_;
      m_run[r] = mnew[r];
    }

    for (int nt = 0; nt < 4; nt++)
      for (int r = 0; r < 4; r++)
        Ps[wid][quad * 4 + r][nt * 16 + l15] = (__bf16)st[nt][r];

    for (int dt = 0; dt < 8; dt++)
      for (int r = 0; r < 4; r++)
        o_acc[dt][r] *= alpha[r];

    __syncthreads();   // P visible; also keeps waves together

    for (int ks2 = 0; ks2 < 2; ks2++) {
      bf16x8 ap = *(const bf16x8*)&Ps[wid][l15][ks2 * 32 + quad * 8];
      for (int dt = 0; dt < 8; dt++) {
        bf16x8 bv = *(const bf16x8*)&Vs[dt * 16 + l15][ks2 * 32 + quad * 8];
        o_acc[dt] = __builtin_amdgcn_mfma_f32_16x16x32_bf16(ap, bv, o_acc[dt], 0, 0, 0);
      }
    }
  }

  size_t trow = (size_t)b * S_ + q0 + wid * 16 + quad * 4;
  for (int dt = 0; dt < 8; dt++) {
    int e = h * D_ + dt * 16 + l15;
    for (int r = 0; r < 4; r++) {
      float val = o_acc[dt][r] / l_run[r];
      attn[(trow + r) * E_ + e] = (__bf16)val;
    }
  }
}

// ---------------------------------------------------------------- launch
extern "C" void kernel_launch(void* const* d_in, const int* in_sizes, int n_in,
                              void* d_out, int out_size, void* d_ws, size_t ws_size,
                              hipStream_t stream) {
  const float* hs    = (const float*)d_in[0];
  const float* qkv_w = (const float*)d_in[1];
  const float* o_w   = (const float*)d_in[2];
  const float* cosb  = (const float*)d_in[3];
  const float* sinb  = (const float*)d_in[4];
  const int*   bt    = (const int*)d_in[7];

  float* out = (float*)d_out;
  float* kc  = out + (size_t)T_ * E_;
  float* vc  = kc + (size_t)B_ * NB_ * H_ * BS_ * D_;

  // ws layout (288 MB): [hsb/attn 32MB][wT 96MB][oT 32MB][q 32][k 32][v 32][vT 32]
  char* ws = (char*)d_ws;
  __bf16* hsb  = (__bf16*)ws;
  __bf16* wT   = (__bf16*)(ws + 33554432);
  __bf16* oT   = wT + (size_t)3 * E_ * E_;
  __bf16* qb   = (__bf16*)(ws + 167772160);
  __bf16* kb   = qb + (size_t)B_ * H_ * S_ * D_;
  __bf16* vb   = kb + (size_t)B_ * H_ * S_ * D_;
  __bf16* vTt  = (__bf16*)(ws + 268435456);
  __bf16* attn = hsb;  // hs no longer needed once attention runs

  k_convert_hs<<<dim3(T_ * E_ / 4 / 256), dim3(256), 0, stream>>>(hs, hsb, T_ * E_ / 4);
  k_transpose_w<<<dim3(128, 128, 3), dim3(256), 0, stream>>>(qkv_w, wT);
  k_transpose_w<<<dim3(128, 128, 1), dim3(256), 0, stream>>>(o_w, oT);
  k_gemm_qkv<<<dim3(32, 96), dim3(256), 0, stream>>>(hsb, wT, qb);
  k_rope<<<dim3(32768), dim3(256), 0, stream>>>(qb, kb, vb, cosb, sinb, bt, kc, vc);
  k_transpose_v<<<dim3(32, 4, 128), dim3(256), 0, stream>>>(vb, vTt);
  k_attn<<<dim3(16, 32, 4), dim3(256), 0, stream>>>(qb, kb, vTt, attn);
  k_gemm_out<<<dim3(32, 32), dim3(256), 0, stream>>>(attn, oT, out);
}

// Round 2
// 1519.045 us; speedup vs baseline: 1.4023x; 1.4023x over previous
//
#include <hip/hip_runtime.h>

#define B_  4
#define S_  1024
#define H_  32
#define D_  128
#define E_  4096
#define T_  4096
#define NB_ 64
#define BS_ 16

typedef __attribute__((ext_vector_type(8))) __bf16 bf16x8;
typedef __attribute__((ext_vector_type(4))) __bf16 bf16x4;
typedef __attribute__((ext_vector_type(4))) float f32x4;

__device__ __forceinline__ void gload_lds16(const __bf16* g, __bf16* l) {
  __builtin_amdgcn_global_load_lds((const __attribute__((address_space(1))) void*)g,
                                   (__attribute__((address_space(3))) void*)l, 16, 0, 0);
}

// ---------------------------------------------------------------- converts
__global__ __launch_bounds__(256) void k_convert_hs(const float* __restrict__ x,
                                                    __bf16* __restrict__ y, int n4) {
  int i = blockIdx.x * 256 + threadIdx.x;
  if (i < n4) {
    float4 v = ((const float4*)x)[i];
    bf16x4 o;
    o[0] = (__bf16)v.x; o[1] = (__bf16)v.y; o[2] = (__bf16)v.z; o[3] = (__bf16)v.w;
    ((bf16x4*)y)[i] = o;
  }
}

// W: [nm][E][E] fp32 (e,f) -> WT: [nm][E][E] bf16 transposed (f,e)
__global__ __launch_bounds__(256) void k_transpose_w(const float* __restrict__ W,
                                                     __bf16* __restrict__ WT) {
  __shared__ float tile[32][33];
  const float* Wm = W + (size_t)blockIdx.z * E_ * E_;
  __bf16* WTm = WT + (size_t)blockIdx.z * E_ * E_;
  int e0 = blockIdx.x * 32, f0 = blockIdx.y * 32;
  int tx = threadIdx.x & 31, ty = threadIdx.x >> 5;
  for (int i = ty; i < 32; i += 8) tile[i][tx] = Wm[(size_t)(e0 + i) * E_ + f0 + tx];
  __syncthreads();
  for (int i = ty; i < 32; i += 8) WTm[(size_t)(f0 + i) * E_ + e0 + tx] = (__bf16)tile[tx][i];
}

// v [b][h][s][d] -> vT [b][h][d][s]  (bf16)
__global__ __launch_bounds__(256) void k_transpose_v(const __bf16* __restrict__ v,
                                                     __bf16* __restrict__ vT) {
  __shared__ __bf16 tile[32][33];
  size_t bh = blockIdx.z;
  const __bf16* vp = v + bh * S_ * D_;
  __bf16* vtp = vT + bh * S_ * D_;
  int s0 = blockIdx.x * 32, d0 = blockIdx.y * 32;
  int tx = threadIdx.x & 31, ty = threadIdx.x >> 5;
  for (int i = ty; i < 32; i += 8) tile[i][tx] = vp[(size_t)(s0 + i) * D_ + d0 + tx];
  __syncthreads();
  for (int i = ty; i < 32; i += 8) vtp[(size_t)(d0 + i) * S_ + s0 + tx] = tile[tx][i];
}

// ---------------------------------------------------------------- RoPE + cache scatter
__global__ __launch_bounds__(256) void k_rope(__bf16* __restrict__ q, __bf16* __restrict__ k,
                                              const __bf16* __restrict__ v,
                                              const float* __restrict__ cosb,
                                              const float* __restrict__ sinb,
                                              const int* __restrict__ bt,
                                              float* __restrict__ kc, float* __restrict__ vc) {
  int idx = blockIdx.x * 256 + threadIdx.x;   // B*H*S*64 = 2^23 threads
  int j = idx & 63;
  int s = (idx >> 6) & (S_ - 1);
  int h = (idx >> 16) & (H_ - 1);
  int b = idx >> 21;
  size_t base = (((size_t)b * H_ + h) * S_ + s) * D_;
  float c  = cosb[(size_t)(b * S_ + s) * 64 + j];
  float sn = sinb[(size_t)(b * S_ + s) * 64 + j];
  float q1 = (float)q[base + j], q2 = (float)q[base + j + 64];
  float k1 = (float)k[base + j], k2 = (float)k[base + j + 64];
  float q1n = q1 * c - q2 * sn, q2n = q2 * c + q1 * sn;
  float k1n = k1 * c - k2 * sn, k2n = k2 * c + k1 * sn;
  q[base + j] = (__bf16)q1n; q[base + j + 64] = (__bf16)q2n;
  k[base + j] = (__bf16)k1n; k[base + j + 64] = (__bf16)k2n;
  int nb = s >> 4, sb = s & 15;
  int blk = bt[b * NB_ + nb];
  size_t cidx = (((size_t)blk * H_ + h) * BS_ + sb) * D_;
  kc[cidx + j] = k1n; kc[cidx + j + 64] = k2n;
  vc[cidx + j] = (float)v[base + j];
  vc[cidx + j + 64] = (float)v[base + j + 64];
}

// ---------------------------------------------------------------- GEMMs (128x128x32, 4 waves)
// A: [M][K] bf16 row-major; BT: [N][K] bf16 row-major (i.e. B transposed)
// m97 structure: global_load_lds width=16 into UNPADDED [128][32] LDS tiles.
#define GEMM_BODY                                                                  \
  __shared__ __align__(16) __bf16 As[128 * 32];                                    \
  __shared__ __align__(16) __bf16 Bs[128 * 32];                                    \
  int tid = threadIdx.x;                                                           \
  int wid = tid >> 6, lane = tid & 63, l15 = lane & 15, quad = lane >> 4;          \
  int wy = wid >> 1, wx = wid & 1;                                                 \
  int m0 = blockIdx.x * 128, n0 = blockIdx.y * 128;                                \
  /* staging: wave wid covers rows [wid*32, wid*32+32): 2 issues of 16 rows */     \
  int srow = wid * 32 + (lane >> 2);                                               \
  int scol = (lane & 3) * 8;                                                       \
  const __bf16* Ag = A + (size_t)(m0 + srow) * E_ + scol;                          \
  const __bf16* Bg = BT + (size_t)(n0 + srow) * E_ + scol;                         \
  __bf16* Al = As + srow * 32 + scol;                                              \
  __bf16* Bl = Bs + srow * 32 + scol;                                              \
  f32x4 acc[4][4] = {};                                                            \
  for (int k0 = 0; k0 < E_; k0 += 32) {                                            \
    gload_lds16(Ag + k0, Al);                                                      \
    gload_lds16(Ag + k0 + (size_t)16 * E_, Al + 16 * 32);                          \
    gload_lds16(Bg + k0, Bl);                                                      \
    gload_lds16(Bg + k0 + (size_t)16 * E_, Bl + 16 * 32);                          \
    __syncthreads();                                                               \
    bf16x8 af[4], bfr[4];                                                          \
    for (int i = 0; i < 4; i++) af[i]  = *(const bf16x8*)&As[(wy * 64 + i * 16 + l15) * 32 + quad * 8]; \
    for (int j = 0; j < 4; j++) bfr[j] = *(const bf16x8*)&Bs[(wx * 64 + j * 16 + l15) * 32 + quad * 8]; \
    for (int i = 0; i < 4; i++)                                                    \
      for (int j = 0; j < 4; j++)                                                  \
        acc[i][j] = __builtin_amdgcn_mfma_f32_16x16x32_bf16(af[i], bfr[j], acc[i][j], 0, 0, 0); \
    __syncthreads();                                                               \
  }

__global__ __launch_bounds__(256) void k_gemm_qkv(const __bf16* __restrict__ A,
                                                  const __bf16* __restrict__ BT,
                                                  __bf16* __restrict__ qkvb) {
  GEMM_BODY
  for (int i = 0; i < 4; i++) {
    int tbase = m0 + wy * 64 + i * 16 + quad * 4;
    for (int j = 0; j < 4; j++) {
      int n = n0 + wx * 64 + j * 16 + l15;      // 0..12287
      int kk = n >> 12, nl = n & 4095;
      int h = nl >> 7, d = nl & 127;
      for (int r = 0; r < 4; r++) {
        int t = tbase + r;
        int bb = t >> 10, s = t & 1023;
        size_t idx = ((((size_t)kk * B_ + bb) * H_ + h) * S_ + s) * D_ + d;
        qkvb[idx] = (__bf16)acc[i][j][r];
      }
    }
  }
}

__global__ __launch_bounds__(256) void k_gemm_out(const __bf16* __restrict__ A,
                                                  const __bf16* __restrict__ BT,
                                                  float* __restrict__ out) {
  GEMM_BODY
  for (int i = 0; i < 4; i++) {
    int tbase = m0 + wy * 64 + i * 16 + quad * 4;
    for (int j = 0; j < 4; j++) {
      int n = n0 + wx * 64 + j * 16 + l15;
      for (int r = 0; r < 4; r++)
        out[(size_t)(tbase + r) * E_ + n] = acc[i][j][r];
    }
  }
}

// ---------------------------------------------------------------- flash attention
// q,k: [b][h][s][d] bf16 (post-RoPE); vT: [b][h][d][s] bf16; attn: [t][e] bf16
__global__ __launch_bounds__(256) void k_attn(const __bf16* __restrict__ q,
                                              const __bf16* __restrict__ k,
                                              const __bf16* __restrict__ vT,
                                              __bf16* __restrict__ attn) {
  __shared__ __align__(16) __bf16 Qs[64][136];
  __shared__ __align__(16) __bf16 Ks[64][136];
  __shared__ __align__(16) __bf16 Vs[128][72];
  __shared__ __align__(16) __bf16 Ps[4][16][72];

  int q0 = blockIdx.x * 64;
  int h = blockIdx.y, b = blockIdx.z;
  int tid = threadIdx.x, wid = tid >> 6, lane = tid & 63, l15 = lane & 15, quad = lane >> 4;

  size_t bh = (size_t)b * H_ + h;
  const __bf16* Qp = q + bh * S_ * D_;
  const __bf16* Kp = k + bh * S_ * D_;
  const __bf16* Vp = vT + bh * (size_t)D_ * S_;

  for (int c = tid; c < 1024; c += 256) {
    int r = c >> 4, dp = (c & 15) * 8;
    *(int4*)&Qs[r][dp] = *(const int4*)&Qp[(size_t)(q0 + r) * D_ + dp];
  }
  __syncthreads();
  bf16x8 aq[4];
  for (int ks = 0; ks < 4; ks++) aq[ks] = *(const bf16x8*)&Qs[wid * 16 + l15][ks * 32 + quad * 8];

  float m_run[4], l_run[4];
  f32x4 o_acc[8] = {};
  for (int r = 0; r < 4; r++) { m_run[r] = -1e30f; l_run[r] = 0.f; }
  const float sm_scale = 0.08838834764831845f;

  int kend = q0 + 64;
  for (int sk0 = 0; sk0 < kend; sk0 += 64) {
    __syncthreads();   // previous iter's Ks/Vs reads done
    for (int c = tid; c < 1024; c += 256) {
      int r = c >> 4, dp = (c & 15) * 8;
      *(int4*)&Ks[r][dp] = *(const int4*)&Kp[(size_t)(sk0 + r) * D_ + dp];
    }
    for (int c = tid; c < 1024; c += 256) {
      int d = c >> 3, sp = (c & 7) * 8;
      *(int4*)&Vs[d][sp] = *(const int4*)&Vp[(size_t)d * S_ + sk0 + sp];
    }
    __syncthreads();

    f32x4 st[4] = {};
    for (int nt = 0; nt < 4; nt++)
      for (int ks = 0; ks < 4; ks++) {
        bf16x8 bk = *(const bf16x8*)&Ks[nt * 16 + l15][ks * 32 + quad * 8];
        st[nt] = __builtin_amdgcn_mfma_f32_16x16x32_bf16(aq[ks], bk, st[nt], 0, 0, 0);
      }

    int qg = q0 + wid * 16 + quad * 4;
    float mnew[4], alpha[4];
    for (int r = 0; r < 4; r++) {
      float rmax = -1e30f;
      for (int nt = 0; nt < 4; nt++) {
        int kg = sk0 + nt * 16 + l15;
        float vsc = st[nt][r] * sm_scale;
        if (kg > qg + r) vsc = -1e30f;
        st[nt][r] = vsc;
        rmax = fmaxf(rmax, vsc);
      }
      for (int off = 1; off < 16; off <<= 1) rmax = fmaxf(rmax, __shfl_xor(rmax, off));
      mnew[r] = fmaxf(m_run[r], rmax);
      alpha[r] = __expf(m_run[r] - mnew[r]);
      float s_ = 0.f;
      for (int nt = 0; nt < 4; nt++) {
        float p = __expf(st[nt][r] - mnew[r]);
        st[nt][r] = p;
        s_ += p;
      }
      for (int off = 1; off < 16; off <<= 1) s_ += __shfl_xor(s_, off);
      l_run[r] = l_run[r] * alpha[r] + s_;
      m_run[r] = mnew[r];
    }

    for (int nt = 0; nt < 4; nt++)
      for (int r = 0; r < 4; r++)
        Ps[wid][quad * 4 + r][nt * 16 + l15] = (__bf16)st[nt][r];

    for (int dt = 0; dt < 8; dt++)
      for (int r = 0; r < 4; r++)
        o_acc[dt][r] *= alpha[r];

    __syncthreads();   // P visible; also keeps waves together

    for (int ks2 = 0; ks2 < 2; ks2++) {
      bf16x8 ap = *(const bf16x8*)&Ps[wid][l15][ks2 * 32 + quad * 8];
      for (int dt = 0; dt < 8; dt++) {
        bf16x8 bv = *(const bf16x8*)&Vs[dt * 16 + l15][ks2 * 32 + quad * 8];
        o_acc[dt] = __builtin_amdgcn_mfma_f32_16x16x32_bf16(ap, bv, o_acc[dt], 0, 0, 0);
      }
    }
  }

  size_t trow = (size_t)b * S_ + q0 + wid * 16 + quad * 4;
  for (int dt = 0; dt < 8; dt++) {
    int e = h * D_ + dt * 16 + l15;
    for (int r = 0; r < 4; r++) {
      float val = o_acc[dt][r] / l_run[r];
      attn[(trow + r) * E_ + e] = (__bf16)val;
    }
  }
}

// ---------------------------------------------------------------- launch
extern "C" void kernel_launch(void* const* d_in, const int* in_sizes, int n_in,
                              void* d_out, int out_size, void* d_ws, size_t ws_size,
                              hipStream_t stream) {
  const float* hs    = (const float*)d_in[0];
  const float* qkv_w = (const float*)d_in[1];
  const float* o_w   = (const float*)d_in[2];
  const float* cosb  = (const float*)d_in[3];
  const float* sinb  = (const float*)d_in[4];
  const int*   bt    = (const int*)d_in[7];

  float* out = (float*)d_out;
  float* kc  = out + (size_t)T_ * E_;
  float* vc  = kc + (size_t)B_ * NB_ * H_ * BS_ * D_;

  // ws layout (288 MB): [hsb/attn 32MB][wT 96MB][oT 32MB][q 32][k 32][v 32][vT 32]
  char* ws = (char*)d_ws;
  __bf16* hsb  = (__bf16*)ws;
  __bf16* wT   = (__bf16*)(ws + 33554432);
  __bf16* oT   = wT + (size_t)3 * E_ * E_;
  __bf16* qb   = (__bf16*)(ws + 167772160);
  __bf16* kb   = qb + (size_t)B_ * H_ * S_ * D_;
  __bf16* vb   = kb + (size_t)B_ * H_ * S_ * D_;
  __bf16* vTt  = (__bf16*)(ws + 268435456);
  __bf16* attn = hsb;  // hs no longer needed once attention runs

  k_convert_hs<<<dim3(T_ * E_ / 4 / 256), dim3(256), 0, stream>>>(hs, hsb, T_ * E_ / 4);
  k_transpose_w<<<dim3(128, 128, 3), dim3(256), 0, stream>>>(qkv_w, wT);
  k_transpose_w<<<dim3(128, 128, 1), dim3(256), 0, stream>>>(o_w, oT);
  k_gemm_qkv<<<dim3(32, 96), dim3(256), 0, stream>>>(hsb, wT, qb);
  k_rope<<<dim3(32768), dim3(256), 0, stream>>>(qb, kb, vb, cosb, sinb, bt, kc, vc);
  k_transpose_v<<<dim3(32, 4, 128), dim3(256), 0, stream>>>(vb, vTt);
  k_attn<<<dim3(16, 32, 4), dim3(256), 0, stream>>>(qb, kb, vTt, attn);
  k_gemm_out<<<dim3(32, 32), dim3(256), 0, stream>>>(attn, oT, out);
}